// Round 3
// baseline (403.013 us; speedup 1.0000x reference)
//
#include <hip/hip_runtime.h>
#include <cstdint>
#include <cstddef>

// Problem constants
#define Bb 8
#define Tt 2048
#define Cc 1024
#define Dd 1024
#define Mm (Bb*Tt)   // 16384 rows
#define CL 64        // wkv chunk length
#define NCH (Tt/CL)  // 32 chunks

// NOTES:
// - inputs/outputs fp32. Workspace layout gated on ws_size>=204MB (merged path).
// - R4: wkv 3-pass parallel scan (318us -> ~40us total).
// - R5: XOR swizzle -> 0 LDS bank conflicts (verified by PMC).
// - R6: 128-tile dbuf merged GEMM: 603 TF, MfmaUtil 26.
// - R7: 256-tile triple-buffer counted vmcnt: 717 TF, MfmaUtil 30.
// - R8: faithful 8-phase port: 713 TF, MfmaUtil 29 == R7. Loose==phased at
//   equal traffic + FETCH 205->74MB with no dt => bottleneck is LDS READ BW:
//   224 KB/K-tile/CU of ds_read_b128 @ ~85 B/cy (m134) = 2635 cy > MFMA 2483.
// - R9: B (weights, 2MB, L2-resident) direct-to-REGISTER from global (AITER
//   buffer_load<->MFMA pattern); A stays in LDS via 3-buffer ring (96 KB),
//   prefetch 2 tiles ahead, uniform vmcnt(8) counted wait. LDS reads drop to
//   128 KB/tile/CU < MFMA time. 1 barrier per K-tile.

typedef __bf16  bf16x8  __attribute__((ext_vector_type(8)));
typedef float   floatx4 __attribute__((ext_vector_type(4)));

#define MFMA16(a, b, c) __builtin_amdgcn_mfma_f32_16x16x32_bf16((a), (b), (c), 0, 0, 0)

__device__ __forceinline__ ushort f2bf(float f) {
    unsigned u = __float_as_uint(f);
    u = (u + 0x7FFF + ((u >> 16) & 1)) >> 16;   // RNE
    return (ushort)u;
}
__device__ __forceinline__ float bf2f(ushort u) {
    return __uint_as_float(((unsigned)u) << 16);
}

__device__ __forceinline__ void load_lds16(const void* g, void* l) {
    __builtin_amdgcn_global_load_lds((__attribute__((address_space(1))) void*)(g),
                                     (__attribute__((address_space(3))) void*)(l),
                                     16, 0, 0);
}

#define CFENCE asm volatile("" ::: "memory")
#define BARRIER do { CFENCE; __builtin_amdgcn_s_barrier(); CFENCE; } while (0)

// ---------------- fused mix + time-shift: fp32 x -> bf16 xk,xv,xr ----------------
__global__ __launch_bounds__(256) void prep_mix3(
        const float* __restrict__ x,
        const float* __restrict__ mk, const float* __restrict__ mv,
        const float* __restrict__ mr,
        ushort* __restrict__ xk, ushort* __restrict__ xv, ushort* __restrict__ xr) {
    int i  = blockIdx.x * 256 + threadIdx.x;     // vec8 chunk id, Mm*Cc/8 total
    int cq = i & (Cc / 8 - 1);                   // 128 vec8 per row
    int m  = i >> 7;
    int t  = m & (Tt - 1);
    float xc[8], xp[8];
    *(float4*)&xc[0] = ((const float4*)x)[i * 2];
    *(float4*)&xc[4] = ((const float4*)x)[i * 2 + 1];
    if (t != 0) {
        *(float4*)&xp[0] = ((const float4*)x)[(i - Cc / 8) * 2];
        *(float4*)&xp[4] = ((const float4*)x)[(i - Cc / 8) * 2 + 1];
    } else {
#pragma unroll
        for (int j = 0; j < 8; j++) xp[j] = 0.f;
    }
    float wk[8], wv[8], wr[8];
    *(float4*)&wk[0] = ((const float4*)mk)[cq * 2];
    *(float4*)&wk[4] = ((const float4*)mk)[cq * 2 + 1];
    *(float4*)&wv[0] = ((const float4*)mv)[cq * 2];
    *(float4*)&wv[4] = ((const float4*)mv)[cq * 2 + 1];
    *(float4*)&wr[0] = ((const float4*)mr)[cq * 2];
    *(float4*)&wr[4] = ((const float4*)mr)[cq * 2 + 1];
    ushort ok[8], ov[8], orr[8];
#pragma unroll
    for (int j = 0; j < 8; j++) {
        float d = xc[j] - xp[j];
        ok[j]  = f2bf(xp[j] + d * wk[j]);
        ov[j]  = f2bf(xp[j] + d * wv[j]);
        orr[j] = f2bf(xp[j] + d * wr[j]);
    }
    ((ulonglong2*)xk)[i] = *(const ulonglong2*)ok;
    ((ulonglong2*)xv)[i] = *(const ulonglong2*)ov;
    ((ulonglong2*)xr)[i] = *(const ulonglong2*)orr;
}

// ---------------- fp32 -> bf16 for the 4 weight matrices ----------------
__global__ __launch_bounds__(256) void cvt_w(
        const float* __restrict__ wk, const float* __restrict__ wv,
        const float* __restrict__ wr, const float* __restrict__ wo,
        ushort* __restrict__ ok, ushort* __restrict__ ov,
        ushort* __restrict__ orr, ushort* __restrict__ oo) {
    int i = blockIdx.x * 256 + threadIdx.x;       // vec4 units, 4 * 2^18 total
    int sel = i >> 18;
    int j = i & ((1 << 18) - 1);
    const float* s = sel == 0 ? wk : sel == 1 ? wv : sel == 2 ? wr : wo;
    ushort* d      = sel == 0 ? ok : sel == 1 ? ov : sel == 2 ? orr : oo;
    float4 f = ((const float4*)s)[j];
    ushort4 o;
    o.x = f2bf(f.x); o.y = f2bf(f.y); o.z = f2bf(f.z); o.w = f2bf(f.w);
    ((ushort4*)d)[j] = o;
}

// ======== R9 GEMM core: 256x256 tile, BK=64, A in LDS ring(3), B in regs ========
// 512 threads = 8 waves (2m x 4n); per-wave output 128x64, acc[8][4] floatx4.
// LDS: A only, 3 buffers x [256][64] bf16 (32 KB each, 96 KB total).
//   Stage: row = j*64 + (tid>>3), src granule pre-swizzled by (row&7);
//   read granule g = (ks*4+quad) ^ (fr&7)  -> conflict-free (R5 family).
// B fragments loaded straight from global (L2-resident weights) into VGPRs,
//   double-buffered one K-tile ahead (bn0/b1 split so last-used regs reload).
// Pipeline per tile T: issue B(T+1).ks0 -> stage A(T+2) -> ks0 reads+32 MFMA
//   -> ks1 reads+32 MFMA -> issue B(T+1).ks1 -> b0=bn0 -> vmcnt(8) -> barrier.
// vmcnt(8) drains A(T+1) (oldest 4 of 16 outstanding); B waits are
// compiler-tracked, so they are safe under any within-tile reordering.
struct Gemm9 {
    floatx4 acc[8][4];
    int quad, fr, wm, wn;

    __device__ __forceinline__ void run(
            const ushort* __restrict__ A, const ushort* __restrict__ Bw,
            long tm, long tn, int Kdim, __bf16* LDSb) {
        const int tid  = threadIdx.x;
        const int lane = tid & 63;
        quad = lane >> 4;
        fr   = lane & 15;
        const int wave = tid >> 6;
        wm = (wave >> 2) * 128;          // m-half: 0 or 128
        wn = (wave & 3) * 64;            // n-col:  0,64,128,192
        const int x7 = fr & 7;
        const int g0 = (quad ^ x7) * 8;          // ks=0 granule elem offset
        const int g1 = ((4 + quad) ^ x7) * 8;    // ks=1

        // ----- A staging addresses (pre-swizzled source, linear LDS dest) -----
        const int srow = tid >> 3;               // 0..63
        const int scol = ((tid & 7) ^ (srow & 7)) * 8;
        const int wlds = wave * 512;             // wave-uniform LDS elem base
        const ushort* Ag[4];
#pragma unroll
        for (int j = 0; j < 4; j++)
            Ag[j] = A + (tm + j * 64 + srow) * (long)Kdim + scol;

        auto stageA = [&](int buf, long koff) {
            __bf16* d = LDSb + buf * 16384;
#pragma unroll
            for (int j = 0; j < 4; j++)
                load_lds16(Ag[j] + koff, d + j * 4096 + wlds);
        };

        // ----- B fragment row pointers (per ni), k-offset added per tile -----
        const ushort* Bq[4];
#pragma unroll
        for (int ni = 0; ni < 4; ni++)
            Bq[ni] = Bw + (tn + wn + ni * 16 + fr) * (long)Kdim + quad * 8;

        floatx4 zero = {0.f, 0.f, 0.f, 0.f};
#pragma unroll
        for (int ai = 0; ai < 8; ai++)
#pragma unroll
            for (int nj = 0; nj < 4; nj++) acc[ai][nj] = zero;

        const int NT = Kdim >> 6;        // K-tiles of 64

        // ----- prologue -----
        stageA(0, 0);                    // A(0): must be the OLDEST vmem ops
        CFENCE;
        if (NT > 1) stageA(1, 64);
        bf16x8 b0[4], b1[4], bn0[4];
#pragma unroll
        for (int ni = 0; ni < 4; ni++) b0[ni] = *(const bf16x8*)(Bq[ni]);
#pragma unroll
        for (int ni = 0; ni < 4; ni++) b1[ni] = *(const bf16x8*)(Bq[ni] + 32);
        // outstanding: A(0)=4 (oldest), then A(1)+B(0)=12 -> drain A(0)
        asm volatile("s_waitcnt vmcnt(12)" ::: "memory");
        BARRIER;

        int bc = 0, bs = 2;
        for (int T = 0; T < NT; ++T) {
            const __bf16* Ab = LDSb + bc * 16384;
            const long knext = (long)(T + 1) * 64;
            if (T + 1 < NT) {
#pragma unroll
                for (int ni = 0; ni < 4; ni++)
                    bn0[ni] = *(const bf16x8*)(Bq[ni] + knext);
            }
            if (T + 2 < NT)
                stageA(bs, (long)(T + 2) * 64);

            bf16x8 a0[4], a1[4];
            // ---------- ks0 (k 0..31 of this tile) ----------
#pragma unroll
            for (int r = 0; r < 4; r++)
                a0[r] = *(const bf16x8*)&Ab[(wm + r * 16 + fr) * 64 + g0];
#pragma unroll
            for (int r = 0; r < 4; r++)
                a1[r] = *(const bf16x8*)&Ab[(wm + 64 + r * 16 + fr) * 64 + g0];
            __builtin_amdgcn_s_setprio(1);
#pragma unroll
            for (int r = 0; r < 4; r++)
#pragma unroll
                for (int ni = 0; ni < 4; ni++)
                    acc[r][ni] = MFMA16(a0[r], b0[ni], acc[r][ni]);
#pragma unroll
            for (int r = 0; r < 4; r++)
#pragma unroll
                for (int ni = 0; ni < 4; ni++)
                    acc[4 + r][ni] = MFMA16(a1[r], b0[ni], acc[4 + r][ni]);
            __builtin_amdgcn_s_setprio(0);
            // ---------- ks1 (k 32..63) ----------
#pragma unroll
            for (int r = 0; r < 4; r++)
                a0[r] = *(const bf16x8*)&Ab[(wm + r * 16 + fr) * 64 + g1];
#pragma unroll
            for (int r = 0; r < 4; r++)
                a1[r] = *(const bf16x8*)&Ab[(wm + 64 + r * 16 + fr) * 64 + g1];
            __builtin_amdgcn_s_setprio(1);
#pragma unroll
            for (int r = 0; r < 4; r++)
#pragma unroll
                for (int ni = 0; ni < 4; ni++)
                    acc[r][ni] = MFMA16(a0[r], b1[ni], acc[r][ni]);
#pragma unroll
            for (int r = 0; r < 4; r++)
#pragma unroll
                for (int ni = 0; ni < 4; ni++)
                    acc[4 + r][ni] = MFMA16(a1[r], b1[ni], acc[4 + r][ni]);
            __builtin_amdgcn_s_setprio(0);

            if (T + 1 < NT) {
#pragma unroll
                for (int ni = 0; ni < 4; ni++)      // b1's last use just ended
                    b1[ni] = *(const bf16x8*)(Bq[ni] + knext + 32);
#pragma unroll
                for (int ni = 0; ni < 4; ni++) b0[ni] = bn0[ni];
                // outstanding <= A(T+1)[4, oldest] + tile-T's <=12 younger:
                // vmcnt(8) drains A(T+1); B protected by compiler waits.
                asm volatile("s_waitcnt vmcnt(8)" ::: "memory");
                BARRIER;
            }
            if (++bc == 3) bc = 0;
            if (++bs == 3) bs = 0;
        }
    }
};

// ---------------- single GEMM (used for Wo, and serial fallback) ----------------
// MODE: 0 = fp32 out, 1 = bf16 out, 2 = bf16 out + sigmoid, 3 = fp16 out
// grid (64, 4): XCD-chunked swizzle, 4 n-tiles of an m-tile adjacent.
template<int MODE>
__global__ __launch_bounds__(512, 2) void gemm_nt(
        const ushort* __restrict__ A, const ushort* __restrict__ Bw,
        void* __restrict__ Co, int Ndim, int Kdim) {
    __shared__ __attribute__((aligned(16))) __bf16 LDSb[3 * 16384];  // 96 KB
    const int orig = blockIdx.y * 64 + blockIdx.x;        // 0..255
    const int L    = (orig & 7) * 32 + (orig >> 3);       // contiguous per XCD
    const long tm = (long)(L >> 2) * 256;
    const long tn = (long)(L & 3) * 256;
    Gemm9 g;
    g.run(A, Bw, tm, tn, Kdim, LDSb);
#pragma unroll
    for (int ai = 0; ai < 8; ai++)
#pragma unroll
        for (int nj = 0; nj < 4; nj++)
#pragma unroll
            for (int r = 0; r < 4; r++) {
                long grow = tm + g.wm + ai * 16 + g.quad * 4 + r;
                long gcol = tn + g.wn + nj * 16 + g.fr;
                float v = g.acc[ai][nj][r];
                if (MODE == 2) v = 1.f / (1.f + __expf(-v));
                if (MODE == 0)      ((float*)Co)[grow * Ndim + gcol] = v;
                else if (MODE == 3) ((_Float16*)Co)[grow * Ndim + gcol] = (_Float16)v;
                else                ((ushort*)Co)[grow * Ndim + gcol] = f2bf(v);
            }
}

// ---------------- merged 3-projection GEMM (needs ws >= 204 MB) ----------------
// grid (64, 12) = 768 blocks; proj-major logical order L = proj*256 + mt*4 + nt,
// chunked 96/XCD so same-A-panel blocks co-reside on one XCD's L2.
__global__ __launch_bounds__(512, 2) void gemm3_nt(
        const ushort* __restrict__ xk, const ushort* __restrict__ xv,
        const ushort* __restrict__ xr,
        const ushort* __restrict__ wk, const ushort* __restrict__ wv,
        const ushort* __restrict__ wr,
        _Float16* __restrict__ kb, ushort* __restrict__ vb,
        ushort* __restrict__ sb) {
    __shared__ __attribute__((aligned(16))) __bf16 LDSb[3 * 16384];  // 96 KB
    const int orig = blockIdx.y * 64 + blockIdx.x;        // 0..767
    const int L    = (orig & 7) * 96 + (orig >> 3);
    const int proj = L >> 8;
    const int rem  = L & 255;
    const long tm = (long)(rem >> 2) * 256;
    const long tn = (long)(rem & 3) * 256;
    const ushort* A  = proj == 0 ? xk : proj == 1 ? xv : xr;
    const ushort* Bw = proj == 0 ? wk : proj == 1 ? wv : wr;
    Gemm9 g;
    g.run(A, Bw, tm, tn, Cc, LDSb);
#pragma unroll
    for (int ai = 0; ai < 8; ai++)
#pragma unroll
        for (int nj = 0; nj < 4; nj++)
#pragma unroll
            for (int r = 0; r < 4; r++) {
                long grow = tm + g.wm + ai * 16 + g.quad * 4 + r;
                long gcol = tn + g.wn + nj * 16 + g.fr;
                long off = grow * Dd + gcol;
                float v = g.acc[ai][nj][r];
                if (proj == 0)      kb[off] = (_Float16)v;
                else if (proj == 1) vb[off] = f2bf(v);
                else                sb[off] = f2bf(1.f / (1.f + __expf(-v)));
            }
}

// ---------------- WKV: 3-pass chunked parallel scan ----------------
__global__ __launch_bounds__(256) void wkv_part(
        const _Float16* __restrict__ kb, const ushort* __restrict__ vb,
        const float* __restrict__ decay,
        float* __restrict__ pa, float* __restrict__ pb) {
    int gid = blockIdx.x * 256 + threadIdx.x;   // 0..B*NCH*D-1, d fastest
    int d = gid & (Dd - 1);
    int c = (gid >> 10) & (NCH - 1);
    int b = gid >> 15;
    float ew = __expf(-__expf(decay[d]));
    size_t base = ((size_t)b * Tt + (size_t)c * CL) * Dd + d;
    float a = 0.f, bs = 0.f;
    for (int i0 = 0; i0 < CL; i0 += 8) {
        float kr[8], vr[8];
#pragma unroll
        for (int j = 0; j < 8; j++) {
            size_t idx = base + (size_t)(i0 + j) * Dd;
            kr[j] = (float)kb[idx]; vr[j] = bf2f(vb[idx]);
        }
#pragma unroll
        for (int j = 0; j < 8; j++) {
            float ek = __expf(kr[j]);
            a  = ew * a  + ek * vr[j];
            bs = ew * bs + ek;
        }
    }
    int sidx = c * (Bb * Dd) + b * Dd + d;      // [c][b][d]
    pa[sidx] = a; pb[sidx] = bs;
}

__global__ __launch_bounds__(256) void wkv_prefix(
        const float* __restrict__ pa, const float* __restrict__ pb,
        const float* __restrict__ decay,
        float* __restrict__ sa, float* __restrict__ sb) {
    int gid = blockIdx.x * 256 + threadIdx.x;   // 0..B*D-1
    int d = gid & (Dd - 1);
    float ewL = __expf(-__expf(decay[d]) * (float)CL);  // ew^CL, direct
    float ca = 0.f, cb = 0.f;
#pragma unroll
    for (int c = 0; c < NCH; c++) {
        int idx = c * (Bb * Dd) + gid;
        sa[idx] = ca; sb[idx] = cb;
        ca = ewL * ca + pa[idx];
        cb = ewL * cb + pb[idx];
    }
}

__global__ __launch_bounds__(256) void wkv_chunk(
        const _Float16* __restrict__ kb, const ushort* __restrict__ vb,
        const ushort* __restrict__ sr,
        const float* __restrict__ decay, const float* __restrict__ tf,
        const float* __restrict__ sa, const float* __restrict__ sb,
        ushort* __restrict__ rw) {
    int gid = blockIdx.x * 256 + threadIdx.x;
    int d = gid & (Dd - 1);
    int c = (gid >> 10) & (NCH - 1);
    int b = gid >> 15;
    float ew = __expf(-__expf(decay[d]));
    float eu = __expf(tf[d]);
    int sidx = c * (Bb * Dd) + b * Dd + d;
    float a = sa[sidx], bs = sb[sidx];
    size_t base = ((size_t)b * Tt + (size_t)c * CL) * Dd + d;
    for (int i0 = 0; i0 < CL; i0 += 8) {
        float kr[8], vr[8], rr[8];
#pragma unroll
        for (int j = 0; j < 8; j++) {
            size_t idx = base + (size_t)(i0 + j) * Dd;
            kr[j] = (float)kb[idx]; vr[j] = bf2f(vb[idx]); rr[j] = bf2f(sr[idx]);
        }
#pragma unroll
        for (int j = 0; j < 8; j++) {
            float ek  = __expf(kr[j]);
            float ekv = ek * vr[j];
            float out = (eu * ekv + a) / (eu * ek + bs);
            a  = ew * a  + ekv;
            bs = ew * bs + ek;
            rw[base + (size_t)(i0 + j) * Dd] = f2bf(rr[j] * out);
        }
    }
}

extern "C" void kernel_launch(void* const* d_in, const int* in_sizes, int n_in,
                              void* d_out, int out_size, void* d_ws, size_t ws_size,
                              hipStream_t stream) {
    (void)in_sizes; (void)n_in; (void)out_size;
    const float* x  = (const float*)d_in[0];
    const float* td = (const float*)d_in[1];
    const float* tf = (const float*)d_in[2];
    const float* mk = (const float*)d_in[3];
    const float* mv = (const float*)d_in[4];
    const float* mr = (const float*)d_in[5];
    const float* Wk = (const float*)d_in[6];
    const float* Wv = (const float*)d_in[7];
    const float* Wr = (const float*)d_in[8];
    const float* Wo = (const float*)d_in[9];
    float* out = (float*)d_out;

    const size_t xsz = (size_t)Mm * Cc * 2;           // 32 MB
    const size_t wsz = (size_t)Dd * Cc * 2;           // 2 MB
    const size_t ssz = (size_t)Bb * NCH * Dd * 4;     // 1 MB
    const size_t need_merged = 6 * xsz + 4 * wsz + 4 * ssz;   // ~204 MB

    char* p = (char*)d_ws;
    auto take = [&](size_t n) { char* r = p; p += n; return r; };
    ushort*   xk = (ushort*)take(xsz);
    ushort*   xv = (ushort*)take(xsz);
    ushort*   xr = (ushort*)take(xsz);
    _Float16* kb = (_Float16*)take(xsz);
    const bool merged = ws_size >= need_merged;
    ushort *vb, *sb, *rw;
    if (merged) {
        vb = (ushort*)take(xsz);
        sb = (ushort*)take(xsz);
        rw = xk;                       // xk dead after gemm3
    } else {
        vb = xk;                       // serial aliasing (R5 layout)
        sb = xv;
        rw = xr;
    }
    ushort* wk = (ushort*)take(wsz);
    ushort* wv = (ushort*)take(wsz);
    ushort* wr = (ushort*)take(wsz);
    ushort* wo = (ushort*)take(wsz);
    float*  pa = (float*)take(ssz);
    float*  pb = (float*)take(ssz);
    float*  sa = (float*)take(ssz);
    float*  sbst = (float*)take(ssz);

    dim3 g1(Mm / 256, Dd / 256);          // (64, 4)
    dim3 g2(Mm / 256, Cc / 256);          // (64, 4)
    dim3 g3(Mm / 256, 3 * Dd / 256);      // (64, 12)
    const int wkv_grid = (Bb * NCH * Dd) / 256;   // 1024

    cvt_w<<<4096, 256, 0, stream>>>(Wk, Wv, Wr, Wo, wk, wv, wr, wo);
    prep_mix3<<<Mm * Cc / 8 / 256, 256, 0, stream>>>(x, mk, mv, mr, xk, xv, xr);

    if (merged) {
        gemm3_nt<<<g3, 512, 0, stream>>>(xk, xv, xr, wk, wv, wr, kb, vb, sb);
    } else {
        gemm_nt<3><<<g1, 512, 0, stream>>>(xk, wk, kb, Dd, Cc);
        gemm_nt<1><<<g1, 512, 0, stream>>>(xv, wv, vb, Dd, Cc);
        gemm_nt<2><<<g1, 512, 0, stream>>>(xr, wr, sb, Dd, Cc);
    }

    wkv_part  <<<wkv_grid, 256, 0, stream>>>(kb, vb, td, pa, pb);
    wkv_prefix<<<(Bb * Dd) / 256, 256, 0, stream>>>(pa, pb, td, sa, sbst);
    wkv_chunk <<<wkv_grid, 256, 0, stream>>>(kb, vb, sb, td, tf, sa, sbst, rw);

    gemm_nt<0><<<g2, 512, 0, stream>>>(rw, wo, out, Cc, Dd);
}

// Round 4
// 376.012 us; speedup vs baseline: 1.0718x; 1.0718x over previous
//
#include <hip/hip_runtime.h>
#include <cstdint>
#include <cstddef>

// Problem constants
#define Bb 8
#define Tt 2048
#define Cc 1024
#define Dd 1024
#define Mm (Bb*Tt)   // 16384 rows
#define CL 64        // wkv chunk length
#define NCH (Tt/CL)  // 32 chunks

// NOTES:
// - inputs/outputs fp32. Workspace layout gated on ws_size>=204MB (merged path).
// - R4: wkv 3-pass parallel scan (318us -> ~40us total).
// - R5: XOR swizzle -> 0 LDS bank conflicts (verified by PMC).
// - R6: 128-tile dbuf merged GEMM: 603 TF, MfmaUtil 26.
// - R7: 256-tile triple-buffer counted vmcnt, coarse: 717 TF, MfmaUtil 30.
// - R8: phased but vmcnt(0)-drain at phase 4: 713 TF == R7 (m218: phases with
//   drain == no phases; counted without phases == no phases).
// - R9: B-to-register: 163us REGRESSION. B fragment loads uncoalesced (16
//   cachelines per dwordx4) -> VMEM transaction storm. Also FALSIFIES the
//   LDS-read-BW theory (halving LDS reads didn't help).
// - R10: the actual m218-proven combo, race-free: BK=32, 3-buffer LDS ring
//   (96 KB), stage distance 2 tiles, 2 phases/tile x 16 MFMA, vmcnt(4) once
//   per tile (never 0 in main loop), 2 raw barriers per phase, setprio
//   around MFMA clusters. Swizzle = PMC-verified R5/R6 family.

typedef __bf16  bf16x8  __attribute__((ext_vector_type(8)));
typedef float   floatx4 __attribute__((ext_vector_type(4)));

#define MFMA16(a, b, c) __builtin_amdgcn_mfma_f32_16x16x32_bf16((a), (b), (c), 0, 0, 0)

__device__ __forceinline__ ushort f2bf(float f) {
    unsigned u = __float_as_uint(f);
    u = (u + 0x7FFF + ((u >> 16) & 1)) >> 16;   // RNE
    return (ushort)u;
}
__device__ __forceinline__ float bf2f(ushort u) {
    return __uint_as_float(((unsigned)u) << 16);
}

__device__ __forceinline__ void load_lds16(const void* g, void* l) {
    __builtin_amdgcn_global_load_lds((__attribute__((address_space(1))) void*)(g),
                                     (__attribute__((address_space(3))) void*)(l),
                                     16, 0, 0);
}

#define CFENCE asm volatile("" ::: "memory")
#define BARRIER do { CFENCE; __builtin_amdgcn_s_barrier(); CFENCE; } while (0)

// ---------------- fused mix + time-shift: fp32 x -> bf16 xk,xv,xr ----------------
__global__ __launch_bounds__(256) void prep_mix3(
        const float* __restrict__ x,
        const float* __restrict__ mk, const float* __restrict__ mv,
        const float* __restrict__ mr,
        ushort* __restrict__ xk, ushort* __restrict__ xv, ushort* __restrict__ xr) {
    int i  = blockIdx.x * 256 + threadIdx.x;     // vec8 chunk id, Mm*Cc/8 total
    int cq = i & (Cc / 8 - 1);                   // 128 vec8 per row
    int m  = i >> 7;
    int t  = m & (Tt - 1);
    float xc[8], xp[8];
    *(float4*)&xc[0] = ((const float4*)x)[i * 2];
    *(float4*)&xc[4] = ((const float4*)x)[i * 2 + 1];
    if (t != 0) {
        *(float4*)&xp[0] = ((const float4*)x)[(i - Cc / 8) * 2];
        *(float4*)&xp[4] = ((const float4*)x)[(i - Cc / 8) * 2 + 1];
    } else {
#pragma unroll
        for (int j = 0; j < 8; j++) xp[j] = 0.f;
    }
    float wk[8], wv[8], wr[8];
    *(float4*)&wk[0] = ((const float4*)mk)[cq * 2];
    *(float4*)&wk[4] = ((const float4*)mk)[cq * 2 + 1];
    *(float4*)&wv[0] = ((const float4*)mv)[cq * 2];
    *(float4*)&wv[4] = ((const float4*)mv)[cq * 2 + 1];
    *(float4*)&wr[0] = ((const float4*)mr)[cq * 2];
    *(float4*)&wr[4] = ((const float4*)mr)[cq * 2 + 1];
    ushort ok[8], ov[8], orr[8];
#pragma unroll
    for (int j = 0; j < 8; j++) {
        float d = xc[j] - xp[j];
        ok[j]  = f2bf(xp[j] + d * wk[j]);
        ov[j]  = f2bf(xp[j] + d * wv[j]);
        orr[j] = f2bf(xp[j] + d * wr[j]);
    }
    ((ulonglong2*)xk)[i] = *(const ulonglong2*)ok;
    ((ulonglong2*)xv)[i] = *(const ulonglong2*)ov;
    ((ulonglong2*)xr)[i] = *(const ulonglong2*)orr;
}

// ---------------- fp32 -> bf16 for the 4 weight matrices ----------------
__global__ __launch_bounds__(256) void cvt_w(
        const float* __restrict__ wk, const float* __restrict__ wv,
        const float* __restrict__ wr, const float* __restrict__ wo,
        ushort* __restrict__ ok, ushort* __restrict__ ov,
        ushort* __restrict__ orr, ushort* __restrict__ oo) {
    int i = blockIdx.x * 256 + threadIdx.x;       // vec4 units, 4 * 2^18 total
    int sel = i >> 18;
    int j = i & ((1 << 18) - 1);
    const float* s = sel == 0 ? wk : sel == 1 ? wv : sel == 2 ? wr : wo;
    ushort* d      = sel == 0 ? ok : sel == 1 ? ov : sel == 2 ? orr : oo;
    float4 f = ((const float4*)s)[j];
    ushort4 o;
    o.x = f2bf(f.x); o.y = f2bf(f.y); o.z = f2bf(f.z); o.w = f2bf(f.w);
    ((ushort4*)d)[j] = o;
}

// ======== R10 GEMM core: 256x256 tile, BK=32, 3-buffer LDS ring ========
// 512 threads = 8 waves (2m x 4n); per-wave output 128x64, acc[8][4] floatx4.
// LDS: 3 buffers x (A[256][32] + B[256][32]) bf16 = 3 x 32 KB = 96 KB.
// Swizzle (R5/R6 family, PMC-verified 0 conflicts): LDS[r][g] holds
// G[r][g ^ ((r>>1)&3)]; staged with pre-swizzled source granule, read with
// granule (quad ^ ((fr>>1)&3)). Max 2-way bank aliasing = free (m136).
// Pipeline (the m218-proven combo: fine phases AND counted-never-0 vmcnt):
//   stage distance = 2 tiles into ring slot (T+2)%3 (retired a full tile ago
//   -> race-free without timing assumptions).
//   ph1: 10 ds_read (a0-7,b0-1) | issue A(T+2) | bar | 16 MFMA [0..7][0..1] | bar
//   ph2:  2 ds_read (b2-3)      | issue B(T+2) | vmcnt(4) -> tile T+1 landed,
//         T+2's 4 loads stay in flight | bar | 16 MFMA [0..7][2..3] | bar
struct GemmR10 {
    floatx4 acc[8][4];
    int quad, fr, wm, wn;

    __device__ __forceinline__ void run(
            const ushort* __restrict__ A, const ushort* __restrict__ Bw,
            long tm, long tn, int Kdim, __bf16* LDSb) {
        const int tid  = threadIdx.x;
        const int lane = tid & 63;
        quad = lane >> 4;
        fr   = lane & 15;
        const int wave = tid >> 6;
        wm = (wave >> 2) * 128;          // m-half: 0 or 128
        wn = (wave & 3) * 64;            // n-col:  0,64,128,192
        const int goff = (quad ^ ((fr >> 1) & 3)) * 8;   // read granule

        // staging: thread covers row tid>>2 (4 threads x 16B = full 64B row),
        // source granule pre-swizzled by ((row>>1)&3) = ((tid>>3)&3)
        const int srow = tid >> 2;               // 0..127
        const int scol = ((tid & 3) ^ ((tid >> 3) & 3)) * 8;
        const int wlds = wave * 512;             // wave-uniform LDS elem base
        const ushort* Ag0 = A  + (tm + srow) * (long)Kdim + scol;
        const ushort* Ag1 = Ag0 + 128 * (long)Kdim;
        const ushort* Bg0 = Bw + (tn + srow) * (long)Kdim + scol;
        const ushort* Bg1 = Bg0 + 128 * (long)Kdim;

        auto stageA = [&](int buf, long ko) {
            __bf16* d = LDSb + buf * 16384;
            load_lds16(Ag0 + ko, d + wlds);
            load_lds16(Ag1 + ko, d + 4096 + wlds);
        };
        auto stageB = [&](int buf, long ko) {
            __bf16* d = LDSb + buf * 16384 + 8192;
            load_lds16(Bg0 + ko, d + wlds);
            load_lds16(Bg1 + ko, d + 4096 + wlds);
        };

        floatx4 zero = {0.f, 0.f, 0.f, 0.f};
#pragma unroll
        for (int ai = 0; ai < 8; ai++)
#pragma unroll
            for (int nj = 0; nj < 4; nj++) acc[ai][nj] = zero;

        const int NT = Kdim >> 5;        // K-tiles of 32

        // prologue: tiles 0 and 1 into ring slots 0,1; drain tile 0 only
        stageA(0, 0);  stageB(0, 0);
        stageA(1, 32); stageB(1, 32);
        asm volatile("s_waitcnt vmcnt(4)" ::: "memory");
        BARRIER;

        int bc = 0;
        for (int T = 0; T < NT; ++T) {
            const __bf16* Ab = LDSb + bc * 16384;
            const __bf16* Bbf = Ab + 8192;
            const int sb = (bc + 2 >= 3) ? bc - 1 : bc + 2;   // (bc+2)%3
            const bool pf = (T + 2 < NT);
            const long ko = (long)(T + 2) * 32;

            bf16x8 a[8], b0, b1, b2, b3;
            // ---------------- phase 1 ----------------
#pragma unroll
            for (int i = 0; i < 8; i++)
                a[i] = *(const bf16x8*)&Ab[(wm + i * 16 + fr) * 32 + goff];
            b0 = *(const bf16x8*)&Bbf[(wn + fr) * 32 + goff];
            b1 = *(const bf16x8*)&Bbf[(wn + 16 + fr) * 32 + goff];
            if (pf) stageA(sb, ko);
            BARRIER;
            __builtin_amdgcn_s_setprio(1);
#pragma unroll
            for (int i = 0; i < 8; i++) {
                acc[i][0] = MFMA16(a[i], b0, acc[i][0]);
                acc[i][1] = MFMA16(a[i], b1, acc[i][1]);
            }
            __builtin_amdgcn_s_setprio(0);
            BARRIER;

            // ---------------- phase 2 ----------------
            b2 = *(const bf16x8*)&Bbf[(wn + 32 + fr) * 32 + goff];
            b3 = *(const bf16x8*)&Bbf[(wn + 48 + fr) * 32 + goff];
            if (pf) stageB(sb, ko);
            if (T + 1 < NT) {
                if (pf) asm volatile("s_waitcnt vmcnt(4)" ::: "memory");
                else    asm volatile("s_waitcnt vmcnt(0)" ::: "memory");
            }
            BARRIER;
            __builtin_amdgcn_s_setprio(1);
#pragma unroll
            for (int i = 0; i < 8; i++) {
                acc[i][2] = MFMA16(a[i], b2, acc[i][2]);
                acc[i][3] = MFMA16(a[i], b3, acc[i][3]);
            }
            __builtin_amdgcn_s_setprio(0);
            BARRIER;

            bc = (bc + 1 == 3) ? 0 : bc + 1;
        }
    }
};

// ---------------- single GEMM (used for Wo, and serial fallback) ----------------
// MODE: 0 = fp32 out, 1 = bf16 out, 2 = bf16 out + sigmoid, 3 = fp16 out
// grid (64, 4): XCD-chunked swizzle, 4 n-tiles of an m-tile adjacent.
template<int MODE>
__global__ __launch_bounds__(512, 2) void gemm_nt(
        const ushort* __restrict__ A, const ushort* __restrict__ Bw,
        void* __restrict__ Co, int Ndim, int Kdim) {
    __shared__ __attribute__((aligned(16))) __bf16 LDSb[3 * 16384];  // 96 KB
    const int orig = blockIdx.y * 64 + blockIdx.x;        // 0..255
    const int L    = (orig & 7) * 32 + (orig >> 3);       // contiguous per XCD
    const long tm = (long)(L >> 2) * 256;
    const long tn = (long)(L & 3) * 256;
    GemmR10 g;
    g.run(A, Bw, tm, tn, Kdim, LDSb);
#pragma unroll
    for (int ai = 0; ai < 8; ai++)
#pragma unroll
        for (int nj = 0; nj < 4; nj++)
#pragma unroll
            for (int r = 0; r < 4; r++) {
                long grow = tm + g.wm + ai * 16 + g.quad * 4 + r;
                long gcol = tn + g.wn + nj * 16 + g.fr;
                float v = g.acc[ai][nj][r];
                if (MODE == 2) v = 1.f / (1.f + __expf(-v));
                if (MODE == 0)      ((float*)Co)[grow * Ndim + gcol] = v;
                else if (MODE == 3) ((_Float16*)Co)[grow * Ndim + gcol] = (_Float16)v;
                else                ((ushort*)Co)[grow * Ndim + gcol] = f2bf(v);
            }
}

// ---------------- merged 3-projection GEMM (needs ws >= 204 MB) ----------------
// grid (64, 12) = 768 blocks; proj-major logical order L = proj*256 + mt*4 + nt,
// chunked 96/XCD so same-A-panel blocks co-reside on one XCD's L2.
__global__ __launch_bounds__(512, 2) void gemm3_nt(
        const ushort* __restrict__ xk, const ushort* __restrict__ xv,
        const ushort* __restrict__ xr,
        const ushort* __restrict__ wk, const ushort* __restrict__ wv,
        const ushort* __restrict__ wr,
        _Float16* __restrict__ kb, ushort* __restrict__ vb,
        ushort* __restrict__ sb) {
    __shared__ __attribute__((aligned(16))) __bf16 LDSb[3 * 16384];  // 96 KB
    const int orig = blockIdx.y * 64 + blockIdx.x;        // 0..767
    const int L    = (orig & 7) * 96 + (orig >> 3);
    const int proj = L >> 8;
    const int rem  = L & 255;
    const long tm = (long)(rem >> 2) * 256;
    const long tn = (long)(rem & 3) * 256;
    const ushort* A  = proj == 0 ? xk : proj == 1 ? xv : xr;
    const ushort* Bw = proj == 0 ? wk : proj == 1 ? wv : wr;
    GemmR10 g;
    g.run(A, Bw, tm, tn, Cc, LDSb);
#pragma unroll
    for (int ai = 0; ai < 8; ai++)
#pragma unroll
        for (int nj = 0; nj < 4; nj++)
#pragma unroll
            for (int r = 0; r < 4; r++) {
                long grow = tm + g.wm + ai * 16 + g.quad * 4 + r;
                long gcol = tn + g.wn + nj * 16 + g.fr;
                long off = grow * Dd + gcol;
                float v = g.acc[ai][nj][r];
                if (proj == 0)      kb[off] = (_Float16)v;
                else if (proj == 1) vb[off] = f2bf(v);
                else                sb[off] = f2bf(1.f / (1.f + __expf(-v)));
            }
}

// ---------------- WKV: 3-pass chunked parallel scan ----------------
__global__ __launch_bounds__(256) void wkv_part(
        const _Float16* __restrict__ kb, const ushort* __restrict__ vb,
        const float* __restrict__ decay,
        float* __restrict__ pa, float* __restrict__ pb) {
    int gid = blockIdx.x * 256 + threadIdx.x;   // 0..B*NCH*D-1, d fastest
    int d = gid & (Dd - 1);
    int c = (gid >> 10) & (NCH - 1);
    int b = gid >> 15;
    float ew = __expf(-__expf(decay[d]));
    size_t base = ((size_t)b * Tt + (size_t)c * CL) * Dd + d;
    float a = 0.f, bs = 0.f;
    for (int i0 = 0; i0 < CL; i0 += 8) {
        float kr[8], vr[8];
#pragma unroll
        for (int j = 0; j < 8; j++) {
            size_t idx = base + (size_t)(i0 + j) * Dd;
            kr[j] = (float)kb[idx]; vr[j] = bf2f(vb[idx]);
        }
#pragma unroll
        for (int j = 0; j < 8; j++) {
            float ek = __expf(kr[j]);
            a  = ew * a  + ek * vr[j];
            bs = ew * bs + ek;
        }
    }
    int sidx = c * (Bb * Dd) + b * Dd + d;      // [c][b][d]
    pa[sidx] = a; pb[sidx] = bs;
}

__global__ __launch_bounds__(256) void wkv_prefix(
        const float* __restrict__ pa, const float* __restrict__ pb,
        const float* __restrict__ decay,
        float* __restrict__ sa, float* __restrict__ sb) {
    int gid = blockIdx.x * 256 + threadIdx.x;   // 0..B*D-1
    int d = gid & (Dd - 1);
    float ewL = __expf(-__expf(decay[d]) * (float)CL);  // ew^CL, direct
    float ca = 0.f, cb = 0.f;
#pragma unroll
    for (int c = 0; c < NCH; c++) {
        int idx = c * (Bb * Dd) + gid;
        sa[idx] = ca; sb[idx] = cb;
        ca = ewL * ca + pa[idx];
        cb = ewL * cb + pb[idx];
    }
}

__global__ __launch_bounds__(256) void wkv_chunk(
        const _Float16* __restrict__ kb, const ushort* __restrict__ vb,
        const ushort* __restrict__ sr,
        const float* __restrict__ decay, const float* __restrict__ tf,
        const float* __restrict__ sa, const float* __restrict__ sb,
        ushort* __restrict__ rw) {
    int gid = blockIdx.x * 256 + threadIdx.x;
    int d = gid & (Dd - 1);
    int c = (gid >> 10) & (NCH - 1);
    int b = gid >> 15;
    float ew = __expf(-__expf(decay[d]));
    float eu = __expf(tf[d]);
    int sidx = c * (Bb * Dd) + b * Dd + d;
    float a = sa[sidx], bs = sb[sidx];
    size_t base = ((size_t)b * Tt + (size_t)c * CL) * Dd + d;
    for (int i0 = 0; i0 < CL; i0 += 8) {
        float kr[8], vr[8], rr[8];
#pragma unroll
        for (int j = 0; j < 8; j++) {
            size_t idx = base + (size_t)(i0 + j) * Dd;
            kr[j] = (float)kb[idx]; vr[j] = bf2f(vb[idx]); rr[j] = bf2f(sr[idx]);
        }
#pragma unroll
        for (int j = 0; j < 8; j++) {
            float ek  = __expf(kr[j]);
            float ekv = ek * vr[j];
            float out = (eu * ekv + a) / (eu * ek + bs);
            a  = ew * a  + ekv;
            bs = ew * bs + ek;
            rw[base + (size_t)(i0 + j) * Dd] = f2bf(rr[j] * out);
        }
    }
}

extern "C" void kernel_launch(void* const* d_in, const int* in_sizes, int n_in,
                              void* d_out, int out_size, void* d_ws, size_t ws_size,
                              hipStream_t stream) {
    (void)in_sizes; (void)n_in; (void)out_size;
    const float* x  = (const float*)d_in[0];
    const float* td = (const float*)d_in[1];
    const float* tf = (const float*)d_in[2];
    const float* mk = (const float*)d_in[3];
    const float* mv = (const float*)d_in[4];
    const float* mr = (const float*)d_in[5];
    const float* Wk = (const float*)d_in[6];
    const float* Wv = (const float*)d_in[7];
    const float* Wr = (const float*)d_in[8];
    const float* Wo = (const float*)d_in[9];
    float* out = (float*)d_out;

    const size_t xsz = (size_t)Mm * Cc * 2;           // 32 MB
    const size_t wsz = (size_t)Dd * Cc * 2;           // 2 MB
    const size_t ssz = (size_t)Bb * NCH * Dd * 4;     // 1 MB
    const size_t need_merged = 6 * xsz + 4 * wsz + 4 * ssz;   // ~204 MB

    char* p = (char*)d_ws;
    auto take = [&](size_t n) { char* r = p; p += n; return r; };
    ushort*   xk = (ushort*)take(xsz);
    ushort*   xv = (ushort*)take(xsz);
    ushort*   xr = (ushort*)take(xsz);
    _Float16* kb = (_Float16*)take(xsz);
    const bool merged = ws_size >= need_merged;
    ushort *vb, *sb, *rw;
    if (merged) {
        vb = (ushort*)take(xsz);
        sb = (ushort*)take(xsz);
        rw = xk;                       // xk dead after gemm3
    } else {
        vb = xk;                       // serial aliasing (R5 layout)
        sb = xv;
        rw = xr;
    }
    ushort* wk = (ushort*)take(wsz);
    ushort* wv = (ushort*)take(wsz);
    ushort* wr = (ushort*)take(wsz);
    ushort* wo = (ushort*)take(wsz);
    float*  pa = (float*)take(ssz);
    float*  pb = (float*)take(ssz);
    float*  sa = (float*)take(ssz);
    float*  sbst = (float*)take(ssz);

    dim3 g1(Mm / 256, Dd / 256);          // (64, 4)
    dim3 g2(Mm / 256, Cc / 256);          // (64, 4)
    dim3 g3(Mm / 256, 3 * Dd / 256);      // (64, 12)
    const int wkv_grid = (Bb * NCH * Dd) / 256;   // 1024

    cvt_w<<<4096, 256, 0, stream>>>(Wk, Wv, Wr, Wo, wk, wv, wr, wo);
    prep_mix3<<<Mm * Cc / 8 / 256, 256, 0, stream>>>(x, mk, mv, mr, xk, xv, xr);

    if (merged) {
        gemm3_nt<<<g3, 512, 0, stream>>>(xk, xv, xr, wk, wv, wr, kb, vb, sb);
    } else {
        gemm_nt<3><<<g1, 512, 0, stream>>>(xk, wk, kb, Dd, Cc);
        gemm_nt<1><<<g1, 512, 0, stream>>>(xv, wv, vb, Dd, Cc);
        gemm_nt<2><<<g1, 512, 0, stream>>>(xr, wr, sb, Dd, Cc);
    }

    wkv_part  <<<wkv_grid, 256, 0, stream>>>(kb, vb, td, pa, pb);
    wkv_prefix<<<(Bb * Dd) / 256, 256, 0, stream>>>(pa, pb, td, sa, sbst);
    wkv_chunk <<<wkv_grid, 256, 0, stream>>>(kb, vb, sb, td, tf, sa, sbst, rw);

    gemm_nt<0><<<g2, 512, 0, stream>>>(rw, wo, out, Cc, Dd);
}